// Round 6
// baseline (173.674 us; speedup 1.0000x reference)
//
#include <hip/hip_runtime.h>
#include <hip/hip_bf16.h>

#define NCOLS 32768
#define NZ 64
#define NT 40
#define DTF 30.0f
#define GAMMAC 0.55f

typedef _Float16 f16;

// Cap the pre-RA scheduler's prefetch window (r4->r5: removed ~200MB of
// scratch-spill HBM traffic caused by hoisted ds_read live ranges).
#define SBAR() __builtin_amdgcn_sched_barrier(0)

// swap lanes (0,1) and (2,3) within each quad: u<->v, t<->s
__device__ __forceinline__ float dpp_swap1(float x) {
    return __int_as_float(__builtin_amdgcn_mov_dpp(__float_as_int(x), 0xB1, 0xF, 0xF, true));
}
__device__ __forceinline__ unsigned int packh2(float a, float b) {
    union { f16 h[2]; unsigned int u; } v;
    v.h[0] = (f16)a; v.h[1] = (f16)b; return v.u;
}
__device__ __forceinline__ unsigned short f16bits(float a) {
    union { f16 h; unsigned short u; } v; v.h = (f16)a; return v.u;
}
__device__ __forceinline__ float lo16f(unsigned int x) {
    union { unsigned int u; f16 h[2]; } v; v.u = x; return (float)v.h[0];
}
__device__ __forceinline__ float hi16f(unsigned int x) {
    union { unsigned int u; f16 h[2]; } v; v.u = x; return (float)v.h[1];
}

// r5 post-mortem: LDS-pipe-bound (192 narrow ds ops/wave-step x 5.8cyc x
// 8 waves/CU x 40 steps = 148us = measured dur). This version:
//  - fg eliminated via linearity: tau' = solve_homog(tau) + r, r precomputed
//    once and held in 32 packed-f16x2 VGPRs (no LDS read in the loop).
//  - W read as b128 (4 levels of (hg,-e) f16x2), CP as b64 (4 levels) ->
//    32 ds ops/wave-step.
//  - LDS 48KB -> 3 blocks/CU (12 waves/CU).
__global__ __launch_bounds__(256, 3) void scm_kernel(
    const float* __restrict__ u0, const float* __restrict__ v0,
    const float* __restrict__ t0, const float* __restrict__ s0,
    const float* __restrict__ hz, const float* __restrict__ akv,
    const float* __restrict__ akt, const float* __restrict__ tfo,
    const float* __restrict__ sfo, const float* __restrict__ uss,
    const float* __restrict__ vss, const float* __restrict__ usb,
    const float* __restrict__ vsb, const float* __restrict__ fcor,
    float* __restrict__ out)
{
    __shared__ uint4 Wsh[16 * 128];   // [k4][pair]: 4 levels (hg,-e) f16x2 = 32KB
    __shared__ uint2 CPsh[16 * 128];  // [k4][pair]: 4 levels -cp f16       = 16KB

    const int ltid  = threadIdx.x;
    const int tid   = blockIdx.x * 256 + ltid;
    const int field = tid & 3;          // 0=u 1=v 2=t 3=s
    const int col   = tid >> 2;
    const int p     = ltid >> 1;        // pair: (u,v) share akv, (t,s) share akt

    const float* ak  = (field < 2) ? akv : akt;
    const float* st0 = (field == 0) ? u0 : (field == 1) ? v0 : (field == 2) ? t0 : s0;

    // per-column Coriolis scalars (u,v only)
    float alpha = 1.0f, beta = 0.0f;
    {
        float fc   = fcor[col];
        float dtfc = DTF * fc;
        float cff  = dtfc * dtfc;
        float cff1 = 1.0f / (1.0f + GAMMAC * GAMMAC * cff);
        float coefc = 1.0f - GAMMAC * (1.0f - GAMMAC) * cff;
        if (field == 0)      { alpha = cff1 * coefc; beta =  cff1 * dtfc; }
        else if (field == 1) { alpha = cff1 * coefc; beta = -cff1 * dtfc; }
    }

    float bnd0 = 0.f, bnd63 = 0.f;
    if (field == 0)      { bnd0 = -DTF * usb[col]; bnd63 = DTF * uss[col]; }
    else if (field == 1) { bnd0 = -DTF * vsb[col]; bnd63 = DTF * vss[col]; }

    const float* hzc = hz + (size_t)col * NZ;
    const float* akc = ak + (size_t)col * (NZ + 1);
    const float* fr  = ((field == 2) ? tfo : sfo) + (size_t)col * NZ;

    // ---- build coefficients (streamed) + forward half of r = M^-1(dt*f) ----
    unsigned int rp[NZ / 2];           // packed f16x2, levels (2j, 2j+1)
    {
        float cpprev = 0.f, aik = 0.f, hk = hzc[0];
        float rdp_prev = 0.f, rdp_even = 0.f;
        uint4 wacc; uint2 cpacc;
        #pragma unroll
        for (int k = 0; k < NZ; ++k) {
            float hk1 = 0.f, aik1 = 0.f;
            if (k < NZ - 1) {
                hk1  = hzc[k + 1];
                aik1 = (-2.0f * DTF) * akc[k + 1] / (hk + hk1);
            }
            float bk    = hk - aik - aik1;
            float denom = bk - aik * cpprev;
            float g     = 1.0f / denom;
            float cpk   = aik1 * g;
            float fgk;
            if (field >= 2) fgk = (DTF * fr[k]) * g;
            else            fgk = (k == 0 ? bnd0 : (k == NZ - 1 ? bnd63 : 0.0f)) * g;
            // forward r-chain (f32): rdp = fg - e*rdp_prev
            float rdp = fmaf(-aik * g, rdp_prev, fgk);
            if ((k & 1) == 0) rdp_even = rdp;
            else              rp[k >> 1] = packh2(rdp_even, rdp);
            rdp_prev = rdp;
            // pack shared coefficients (even thread of the pair publishes)
            unsigned int wv  = packh2(hk * g, -aik * g);
            unsigned short cv = f16bits(-cpk);
            switch (k & 3) {
                case 0: wacc.x = wv; cpacc.x = cv; break;
                case 1: wacc.y = wv; cpacc.x |= ((unsigned int)cv << 16); break;
                case 2: wacc.z = wv; cpacc.y = cv; break;
                default:
                    wacc.w = wv; cpacc.y |= ((unsigned int)cv << 16);
                    if ((ltid & 1) == 0) {
                        Wsh[(k >> 2) * 128 + p]  = wacc;
                        CPsh[(k >> 2) * 128 + p] = cpacc;
                    }
                    break;
            }
            cpprev = cpk; aik = aik1; hk = hk1;
            if ((k & 15) == 15) SBAR();
        }
    }

    // ---- load state ----
    float tau[NZ];
    {
        const float4* sp = (const float4*)(st0 + (size_t)col * NZ);
        #pragma unroll
        for (int k4 = 0; k4 < NZ / 4; ++k4) {
            float4 s = sp[k4];
            tau[4*k4+0] = s.x; tau[4*k4+1] = s.y;
            tau[4*k4+2] = s.z; tau[4*k4+3] = s.w;
        }
    }

    // deviation shift for t,s (solve conserves constants exactly): evolve
    // tau = state - mean, re-add at the end -> f16 coefficient rounding
    // cannot excite the conserved mode.
    float meanadd = 0.0f;
    if (field >= 2) {
        float ssum = 0.f;
        #pragma unroll
        for (int k = 0; k < NZ; ++k) ssum += tau[k];
        meanadd = ssum * (1.0f / NZ);
        #pragma unroll
        for (int k = 0; k < NZ; ++k) tau[k] -= meanadd;
    }

    __syncthreads();   // coefficients published; LDS read-only from here on

    // ---- backward half of r (needs cp from LDS), repack into rp ----
    {
        float rx = 0.f;
        #pragma unroll
        for (int k4 = 15; k4 >= 0; --k4) {
            uint2 cp4 = CPsh[k4 * 128 + p];
            float rd0 = lo16f(rp[2*k4]),   rd1 = hi16f(rp[2*k4]);
            float rd2 = lo16f(rp[2*k4+1]), rd3 = hi16f(rp[2*k4+1]);
            float x3 = fmaf(hi16f(cp4.y), rx, rd3);
            float x2 = fmaf(lo16f(cp4.y), x3, rd2);
            float x1 = fmaf(hi16f(cp4.x), x2, rd1);
            float x0 = fmaf(lo16f(cp4.x), x1, rd0);
            rp[2*k4]   = packh2(x0, x1);
            rp[2*k4+1] = packh2(x2, x3);
            rx = x0;
            if ((k4 & 3) == 0) SBAR();
        }
    }

    // ---- 40 time steps ----
    for (int n = 0; n < NT; ++n) {
        float dpprev = 0.f;
        #pragma unroll
        for (int k4 = 0; k4 < 16; ++k4) {
            uint4 w = Wsh[k4 * 128 + p];
            #pragma unroll
            for (int j = 0; j < 4; ++j) {
                unsigned int wv = (j == 0) ? w.x : (j == 1) ? w.y : (j == 2) ? w.z : w.w;
                float own = tau[4*k4 + j];
                float oth = dpp_swap1(own);               // partner field
                float m   = fmaf(beta, oth, alpha * own); // t,s: beta=0,alpha=1
                float dp  = fmaf(hi16f(wv), dpprev, lo16f(wv) * m); // hg*m - e*dpprev
                tau[4*k4 + j] = dp;
                dpprev = dp;
            }
            if ((k4 & 3) == 3) SBAR();
        }
        float xn = 0.f;
        #pragma unroll
        for (int k4 = 15; k4 >= 0; --k4) {
            uint2 cp4 = CPsh[k4 * 128 + p];
            unsigned int r01 = rp[2*k4], r23 = rp[2*k4+1];
            float x3 = fmaf(hi16f(cp4.y), xn, tau[4*k4+3]);
            tau[4*k4+3] = x3 + hi16f(r23);
            float x2 = fmaf(lo16f(cp4.y), x3, tau[4*k4+2]);
            tau[4*k4+2] = x2 + lo16f(r23);
            float x1 = fmaf(hi16f(cp4.x), x2, tau[4*k4+1]);
            tau[4*k4+1] = x1 + hi16f(r01);
            float x0 = fmaf(lo16f(cp4.x), x1, tau[4*k4+0]);
            tau[4*k4+0] = x0 + lo16f(r01);
            xn = x0;
            if ((k4 & 3) == 0) SBAR();
        }
    }

    // ---- store f32 output: out[field][col][k] ----
    float* op = out + ((size_t)field * NCOLS + col) * NZ;
    #pragma unroll
    for (int k4 = 0; k4 < NZ / 4; ++k4) {
        float4 w;
        w.x = tau[4*k4+0] + meanadd;
        w.y = tau[4*k4+1] + meanadd;
        w.z = tau[4*k4+2] + meanadd;
        w.w = tau[4*k4+3] + meanadd;
        ((float4*)op)[k4] = w;
    }
}

extern "C" void kernel_launch(void* const* d_in, const int* in_sizes, int n_in,
                              void* d_out, int out_size, void* d_ws, size_t ws_size,
                              hipStream_t stream) {
    const float* u0   = (const float*)d_in[0];
    const float* v0   = (const float*)d_in[1];
    const float* t0   = (const float*)d_in[2];
    const float* s0   = (const float*)d_in[3];
    const float* hz   = (const float*)d_in[4];
    const float* akv  = (const float*)d_in[5];
    const float* akt  = (const float*)d_in[6];
    const float* tfo  = (const float*)d_in[7];
    const float* sfo  = (const float*)d_in[8];
    const float* uss  = (const float*)d_in[9];
    const float* vss  = (const float*)d_in[10];
    const float* usb  = (const float*)d_in[11];
    const float* vsb  = (const float*)d_in[12];
    const float* fcor = (const float*)d_in[13];

    scm_kernel<<<dim3((NCOLS * 4) / 256), dim3(256), 0, stream>>>(
        u0, v0, t0, s0, hz, akv, akt, tfo, sfo, uss, vss, usb, vsb, fcor,
        (float*)d_out);
}

// Round 7
// 126.440 us; speedup vs baseline: 1.3736x; 1.3736x over previous
//
#include <hip/hip_runtime.h>
#include <hip/hip_bf16.h>

#define NCOLS 32768
#define NZ 64
#define NT 40
#define DTF 30.0f
#define GAMMAC 0.55f

typedef _Float16 f16;

// Cap the pre-RA scheduler's prefetch window (r4->r5: removed ~200MB of
// scratch-spill HBM traffic caused by hoisted ds_read live ranges).
#define SBAR() __builtin_amdgcn_sched_barrier(0)

// swap lanes (0,1) and (2,3) within each quad: u<->v, t<->s
__device__ __forceinline__ float dpp_swap1(float x) {
    return __int_as_float(__builtin_amdgcn_mov_dpp(__float_as_int(x), 0xB1, 0xF, 0xF, true));
}
__device__ __forceinline__ unsigned int packh2(float a, float b) {
    union { f16 h[2]; unsigned int u; } v;
    v.h[0] = (f16)a; v.h[1] = (f16)b; return v.u;
}
__device__ __forceinline__ unsigned short f16bits(float a) {
    union { f16 h; unsigned short u; } v; v.h = (f16)a; return v.u;
}
__device__ __forceinline__ float lo16f(unsigned int x) {
    union { unsigned int u; f16 h[2]; } v; v.u = x; return (float)v.h[0];
}
__device__ __forceinline__ float hi16f(unsigned int x) {
    union { unsigned int u; f16 h[2]; } v; v.u = x; return (float)v.h[1];
}

// History: r2/r3/r6 prove the allocator caps this kernel at ~88 VGPRs
// (occupancy heuristic) and spills anything bigger -> every design must fit
// ~88 regs. r5 (88 VGPR, no spill) was LDS-ISSUE-bound: 192 narrow ds ops/
// wave-step. r6 (fg->registers) re-spilled (+120MB scratch). This version
// keeps r5's register footprint and instead WIDENS the LDS reads:
//   W  = 16x ds_read_b128 (4 levels (hg,-e) f16x2, pair-shared)
//   FG = 16x ds_read_b64  (4 levels f16, per-thread)
//   CP = 16x ds_read_b64  (4 levels f16, pair-shared)
// -> 48 ds ops/wave-step (was 192). LDS 80KB -> 2 blocks/CU as r5.
__global__ __launch_bounds__(256, 2) void scm_kernel(
    const float* __restrict__ u0, const float* __restrict__ v0,
    const float* __restrict__ t0, const float* __restrict__ s0,
    const float* __restrict__ hz, const float* __restrict__ akv,
    const float* __restrict__ akt, const float* __restrict__ tfo,
    const float* __restrict__ sfo, const float* __restrict__ uss,
    const float* __restrict__ vss, const float* __restrict__ usb,
    const float* __restrict__ vsb, const float* __restrict__ fcor,
    float* __restrict__ out)
{
    __shared__ uint4 Wsh[16 * 128];   // [k4][pair] 4 levels (hg,-e) = 32KB
    __shared__ uint2 CPsh[16 * 128];  // [k4][pair] 4 levels -cp     = 16KB
    __shared__ uint2 FGsh[16 * 256];  // [k4][thread] 4 levels fg    = 32KB

    const int ltid  = threadIdx.x;
    const int tid   = blockIdx.x * 256 + ltid;
    const int field = tid & 3;          // 0=u 1=v 2=t 3=s
    const int col   = tid >> 2;
    const int p     = ltid >> 1;        // pair: (u,v) share akv, (t,s) share akt

    const float* ak  = (field < 2) ? akv : akt;
    const float* st0 = (field == 0) ? u0 : (field == 1) ? v0 : (field == 2) ? t0 : s0;

    // per-column Coriolis scalars (u,v only)
    float alpha = 1.0f, beta = 0.0f;
    {
        float fc   = fcor[col];
        float dtfc = DTF * fc;
        float cff  = dtfc * dtfc;
        float cff1 = 1.0f / (1.0f + GAMMAC * GAMMAC * cff);
        float coefc = 1.0f - GAMMAC * (1.0f - GAMMAC) * cff;
        if (field == 0)      { alpha = cff1 * coefc; beta =  cff1 * dtfc; }
        else if (field == 1) { alpha = cff1 * coefc; beta = -cff1 * dtfc; }
    }

    float bnd0 = 0.f, bnd63 = 0.f;
    if (field == 0)      { bnd0 = -DTF * usb[col]; bnd63 = DTF * uss[col]; }
    else if (field == 1) { bnd0 = -DTF * vsb[col]; bnd63 = DTF * vss[col]; }

    const float* hzc = hz + (size_t)col * NZ;
    const float* akc = ak + (size_t)col * (NZ + 1);
    const float* fr  = ((field == 2) ? tfo : sfo) + (size_t)col * NZ;

    // ---- build folded Thomas coefficients, STREAMED, packed 4 levels/write ----
    // a[k] = -2dt*ak[k]/(hz[k-1]+hz[k]); c[k]=a[k+1]; b[k]=hz[k]-a[k]-c[k]
    // g=1/(b-a*cp_prev); publish hg=hz*g, e=a*g, cp=c*g, fg=rhs*g (f16)
    {
        float cpprev = 0.f, aik = 0.f, hk = hzc[0];
        uint4 wacc; uint2 cpacc, fgacc;
        #pragma unroll
        for (int k = 0; k < NZ; ++k) {
            float hk1 = 0.f, aik1 = 0.f;
            if (k < NZ - 1) {
                hk1  = hzc[k + 1];
                aik1 = (-2.0f * DTF) * akc[k + 1] / (hk + hk1);
            }
            float bk    = hk - aik - aik1;
            float denom = bk - aik * cpprev;
            float g     = 1.0f / denom;
            float cpk   = aik1 * g;
            float fgk;
            if (field >= 2) fgk = (DTF * fr[k]) * g;
            else            fgk = (k == 0 ? bnd0 : (k == NZ - 1 ? bnd63 : 0.0f)) * g;
            unsigned int   wv = packh2(hk * g, -aik * g);
            unsigned short cv = f16bits(-cpk);
            unsigned short fv = f16bits(fgk);
            switch (k & 3) {
                case 0: wacc.x = wv; cpacc.x = cv; fgacc.x = fv; break;
                case 1: wacc.y = wv; cpacc.x |= ((unsigned int)cv << 16);
                        fgacc.x |= ((unsigned int)fv << 16); break;
                case 2: wacc.z = wv; cpacc.y = cv; fgacc.y = fv; break;
                default:
                    wacc.w = wv; cpacc.y |= ((unsigned int)cv << 16);
                    fgacc.y |= ((unsigned int)fv << 16);
                    FGsh[(k >> 2) * 256 + ltid] = fgacc;
                    if ((ltid & 1) == 0) {
                        Wsh[(k >> 2) * 128 + p]  = wacc;
                        CPsh[(k >> 2) * 128 + p] = cpacc;
                    }
                    break;
            }
            cpprev = cpk; aik = aik1; hk = hk1;
            if ((k & 15) == 15) SBAR();
        }
    }

    // ---- load state ----
    float tau[NZ];
    {
        const float4* sp = (const float4*)(st0 + (size_t)col * NZ);
        #pragma unroll
        for (int k4 = 0; k4 < NZ / 4; ++k4) {
            float4 s = sp[k4];
            tau[4*k4+0] = s.x; tau[4*k4+1] = s.y;
            tau[4*k4+2] = s.z; tau[4*k4+3] = s.w;
        }
    }

    // deviation shift for t,s (solve conserves constants exactly): evolve
    // tau = state - mean, re-add at the end -> f16 coefficient rounding
    // cannot excite the conserved mode.
    float meanadd = 0.0f;
    if (field >= 2) {
        float ssum = 0.f;
        #pragma unroll
        for (int k = 0; k < NZ; ++k) ssum += tau[k];
        meanadd = ssum * (1.0f / NZ);
        #pragma unroll
        for (int k = 0; k < NZ; ++k) tau[k] -= meanadd;
    }

    __syncthreads();   // coefficients published; LDS read-only from here on

    // ---- 40 time steps: tau in registers, coefficients via wide LDS reads ----
    for (int n = 0; n < NT; ++n) {
        float dpprev = 0.f;
        #pragma unroll
        for (int k4 = 0; k4 < 16; ++k4) {
            uint4 w   = Wsh[k4 * 128 + p];
            uint2 fg4 = FGsh[k4 * 256 + ltid];
            #pragma unroll
            for (int j = 0; j < 4; ++j) {
                unsigned int wv = (j == 0) ? w.x : (j == 1) ? w.y : (j == 2) ? w.z : w.w;
                float fgv = (j == 0) ? lo16f(fg4.x) : (j == 1) ? hi16f(fg4.x)
                          : (j == 2) ? lo16f(fg4.y) : hi16f(fg4.y);
                float own = tau[4*k4 + j];
                float oth = dpp_swap1(own);               // partner field
                float m   = fmaf(beta, oth, alpha * own); // t,s: beta=0,alpha=1
                float dp  = fmaf(lo16f(wv), m, fgv);      // hg*m + fg
                dp = fmaf(hi16f(wv), dpprev, dp);         // - e*dp_prev
                tau[4*k4 + j] = dp;
                dpprev = dp;
            }
            if ((k4 & 3) == 3) SBAR();
        }
        float xn = 0.f;
        #pragma unroll
        for (int k4 = 15; k4 >= 0; --k4) {
            uint2 cp4 = CPsh[k4 * 128 + p];
            float x3 = fmaf(hi16f(cp4.y), xn, tau[4*k4+3]); tau[4*k4+3] = x3;
            float x2 = fmaf(lo16f(cp4.y), x3, tau[4*k4+2]); tau[4*k4+2] = x2;
            float x1 = fmaf(hi16f(cp4.x), x2, tau[4*k4+1]); tau[4*k4+1] = x1;
            float x0 = fmaf(lo16f(cp4.x), x1, tau[4*k4+0]); tau[4*k4+0] = x0;
            xn = x0;
            if ((k4 & 3) == 0) SBAR();
        }
    }

    // ---- store f32 output: out[field][col][k] ----
    float* op = out + ((size_t)field * NCOLS + col) * NZ;
    #pragma unroll
    for (int k4 = 0; k4 < NZ / 4; ++k4) {
        float4 w;
        w.x = tau[4*k4+0] + meanadd;
        w.y = tau[4*k4+1] + meanadd;
        w.z = tau[4*k4+2] + meanadd;
        w.w = tau[4*k4+3] + meanadd;
        ((float4*)op)[k4] = w;
    }
}

extern "C" void kernel_launch(void* const* d_in, const int* in_sizes, int n_in,
                              void* d_out, int out_size, void* d_ws, size_t ws_size,
                              hipStream_t stream) {
    const float* u0   = (const float*)d_in[0];
    const float* v0   = (const float*)d_in[1];
    const float* t0   = (const float*)d_in[2];
    const float* s0   = (const float*)d_in[3];
    const float* hz   = (const float*)d_in[4];
    const float* akv  = (const float*)d_in[5];
    const float* akt  = (const float*)d_in[6];
    const float* tfo  = (const float*)d_in[7];
    const float* sfo  = (const float*)d_in[8];
    const float* uss  = (const float*)d_in[9];
    const float* vss  = (const float*)d_in[10];
    const float* usb  = (const float*)d_in[11];
    const float* vsb  = (const float*)d_in[12];
    const float* fcor = (const float*)d_in[13];

    scm_kernel<<<dim3((NCOLS * 4) / 256), dim3(256), 0, stream>>>(
        u0, v0, t0, s0, hz, akv, akt, tfo, sfo, uss, vss, usb, vsb, fcor,
        (float*)d_out);
}